// Round 12
// baseline (279.016 us; speedup 1.0000x reference)
//
#include <hip/hip_runtime.h>

#define DEV __device__ __forceinline__

typedef float f32x4 __attribute__((ext_vector_type(4)));
typedef short s16x4 __attribute__((ext_vector_type(4)));
typedef short s16x8 __attribute__((ext_vector_type(8)));

DEV float bf2f(short s) {
  unsigned u = ((unsigned)(unsigned short)s) << 16;
  return __builtin_bit_cast(float, u);
}
DEV short f2bf(float f) {
  unsigned u = __builtin_bit_cast(unsigned, f);
  u += 0x7FFFu + ((u >> 16) & 1u);   // RNE
  return (short)(u >> 16);
}

DEV void gld_lds16(const void* g, void* l) {
  __builtin_amdgcn_global_load_lds(
      (const __attribute__((address_space(1))) void*)g,
      (__attribute__((address_space(3))) void*)l, 16, 0, 0);
}

// ---------------- fused front-end, 2048 blocks = 1 dispatch round (r10 ordering) ----------------
// INTERLEAVED bucket rows: row d = [cnt | srcs...] so the fill's atomic (on slot 0) and the
// slot store land in the same 256B row (same 64B line for p<15) -> ~2x fewer random-line
// touches vs separate cnt[] + bucket[]. Region is pre-zeroed by one memset.
// blocks [0,1664): conv | [1664,1728): both W^T | [1728,2016): fill0 | [2016,2048): fill1
__global__ void front_k(const float* __restrict__ feat, short* __restrict__ fbf, long nconv,
                        const float* __restrict__ Ws0, const float* __restrict__ Wn0,
                        short* __restrict__ W0T,
                        const float* __restrict__ Ws1, const float* __restrict__ Wn1,
                        short* __restrict__ W1T,
                        const int* __restrict__ es0, const int* __restrict__ ed0, int E0,
                        int* __restrict__ bk0,
                        const int* __restrict__ es1, const int* __restrict__ ed1, int E1,
                        int* __restrict__ bk1) {
  const int b = blockIdx.x, tid = threadIdx.x;
  if (b < 1664) {
    long i = ((long)b * 256 + tid) * 8;
    const long stride = (long)1664 * 256 * 8;
    for (; i < nconv; i += stride) {
      f32x4 v0 = *(const f32x4*)(feat + i);
      f32x4 v1 = *(const f32x4*)(feat + i + 4);
      s16x8 o;
      o[0] = f2bf(v0[0]); o[1] = f2bf(v0[1]); o[2] = f2bf(v0[2]); o[3] = f2bf(v0[3]);
      o[4] = f2bf(v1[0]); o[5] = f2bf(v1[1]); o[6] = f2bf(v1[2]); o[7] = f2bf(v1[3]);
      *(s16x8*)(fbf + i) = o;
    }
  } else if (b < 1728) {
    // combined W^T: idx in [0, 524288); first 262144 -> W0T (N=512,K=512), rest -> W1T (N=256,K=1024)
    for (int idx = (b - 1664) * 256 + tid; idx < 524288; idx += 64 * 256) {
      if (idx < 262144) {
        int n = idx >> 9, k = idx & 511;
        float v = (k < 256) ? Ws0[(size_t)k * 512 + n] : Wn0[(size_t)(k - 256) * 512 + n];
        W0T[idx] = f2bf(v);
      } else {
        int i2 = idx - 262144;
        int n = i2 >> 10, k = i2 & 1023;
        float v = (k < 512) ? Ws1[(size_t)k * 256 + n] : Wn1[(size_t)(k - 512) * 256 + n];
        W1T[i2] = f2bf(v);
      }
    }
  } else if (b < 2016) {
    for (int e = (b - 1728) * 256 + tid; e < E0; e += 288 * 256) {
      int d = ed0[e];
      int base = d << 6;                     // row = [cnt | 63 slots]
      int p = atomicAdd(&bk0[base], 1);
      if (p < 63) bk0[base + 1 + p] = es0[e];
    }
  } else {
    for (int e = (b - 2016) * 256 + tid; e < E1; e += 32 * 256) {
      int d = ed1[e];
      int base = d * 48;                     // row = [cnt | 47 slots]
      int p = atomicAdd(&bk1[base], 1);
      if (p < 47) bk1[base + 1 + p] = es1[e];
    }
  }
}

// ---------------- mean aggregation: one wave per dst row (interleaved bucket rows) ----------------
__global__ void agg_f32_256(const float* __restrict__ X, const int* __restrict__ bucket,
                            short* __restrict__ out, int n_dst) {
  int gw = (blockIdx.x * blockDim.x + threadIdx.x) >> 6;
  if (gw >= n_dst) return;
  int lane = threadIdx.x & 63;
  int start = gw << 6;
  int cnt = min(bucket[start], 63);
  const int bs = start + 1;
  float a[4] = {0, 0, 0, 0}, b[4] = {0, 0, 0, 0};
  int i = 0;
  for (; i + 2 <= cnt; i += 2) {
    int s0 = bucket[bs + i], s1 = bucket[bs + i + 1];
    f32x4 v0 = *(const f32x4*)(X + (size_t)s0 * 256 + lane * 4);
    f32x4 v1 = *(const f32x4*)(X + (size_t)s1 * 256 + lane * 4);
#pragma unroll
    for (int j = 0; j < 4; ++j) { a[j] += v0[j]; b[j] += v1[j]; }
  }
  if (i < cnt) {
    int s0 = bucket[bs + i];
    f32x4 v0 = *(const f32x4*)(X + (size_t)s0 * 256 + lane * 4);
#pragma unroll
    for (int j = 0; j < 4; ++j) a[j] += v0[j];
  }
  float inv = 1.0f / (float)(cnt > 0 ? cnt : 1);
  s16x4 o;
#pragma unroll
  for (int j = 0; j < 4; ++j) o[j] = f2bf((a[j] + b[j]) * inv);
  *(s16x4*)(out + (size_t)gw * 256 + lane * 4) = o;
}

// 2-rows-per-instruction: lanes 0..31 even-slot, 32..63 odd-slot, 16 B/lane; cross-half
// shfl reduce at the end. (r8-verified loop structure; bucket row = [cnt | slots].)
__global__ void agg_bf16_256(const short* __restrict__ X, const int* __restrict__ bucket,
                             short* __restrict__ out, int n_dst) {
  int gw = (blockIdx.x * blockDim.x + threadIdx.x) >> 6;
  if (gw >= n_dst) return;
  int lane = threadIdx.x & 63;
  int half = lane >> 5;        // which neighbor of the pair
  int cl = lane & 31;          // column group: cols cl*8 .. cl*8+7
  int start = gw << 6;
  int cnt = min(bucket[start], 63);
  const int bs = start + 1;
  float a[8] = {0, 0, 0, 0, 0, 0, 0, 0}, b[8] = {0, 0, 0, 0, 0, 0, 0, 0};
  int i = 0;
  for (; i + 4 <= cnt; i += 4) {
    int s0 = bucket[bs + i + half];
    int s1 = bucket[bs + i + 2 + half];
    s16x8 v0 = *(const s16x8*)(X + (size_t)s0 * 256 + cl * 8);
    s16x8 v1 = *(const s16x8*)(X + (size_t)s1 * 256 + cl * 8);
#pragma unroll
    for (int j = 0; j < 8; ++j) { a[j] += bf2f(v0[j]); b[j] += bf2f(v1[j]); }
  }
  for (; i < cnt; i += 2) {            // tail: 1..3 neighbors, half-predicated
    int idx = i + half;
    if (idx < cnt) {
      int s0 = bucket[bs + idx];
      s16x8 v0 = *(const s16x8*)(X + (size_t)s0 * 256 + cl * 8);
#pragma unroll
      for (int j = 0; j < 8; ++j) a[j] += bf2f(v0[j]);
    }
  }
  float inv = 1.0f / (float)(cnt > 0 ? cnt : 1);
  float r[8];
#pragma unroll
  for (int j = 0; j < 8; ++j) {
    float s = a[j] + b[j];
    r[j] = s + __shfl(s, lane ^ 32);   // combine the two neighbor subsets
  }
  if (half == 0) {
    s16x8 o;
#pragma unroll
    for (int j = 0; j < 8; ++j) o[j] = f2bf(r[j] * inv);
    *(s16x8*)(out + (size_t)gw * 256 + cl * 8) = o;
  }
}

// D=512: 16 B/lane across all 64 lanes; MLP via unroll-4. Bucket row = 48 ints [cnt | 47 slots].
__global__ void agg_bf16_512(const short* __restrict__ X, const int* __restrict__ bucket,
                             short* __restrict__ out, int n_dst) {
  int gw = (blockIdx.x * blockDim.x + threadIdx.x) >> 6;
  if (gw >= n_dst) return;
  int lane = threadIdx.x & 63;
  int start = gw * 48;
  int cnt = min(bucket[start], 47);
  const int bs = start + 1;
  float a[8] = {0, 0, 0, 0, 0, 0, 0, 0}, b[8] = {0, 0, 0, 0, 0, 0, 0, 0};
  float c[8] = {0, 0, 0, 0, 0, 0, 0, 0}, d[8] = {0, 0, 0, 0, 0, 0, 0, 0};
  int i = 0;
  for (; i + 4 <= cnt; i += 4) {
    int s0 = bucket[bs + i], s1 = bucket[bs + i + 1];
    int s2 = bucket[bs + i + 2], s3 = bucket[bs + i + 3];
    s16x8 v0 = *(const s16x8*)(X + (size_t)s0 * 512 + lane * 8);
    s16x8 v1 = *(const s16x8*)(X + (size_t)s1 * 512 + lane * 8);
    s16x8 v2 = *(const s16x8*)(X + (size_t)s2 * 512 + lane * 8);
    s16x8 v3 = *(const s16x8*)(X + (size_t)s3 * 512 + lane * 8);
#pragma unroll
    for (int j = 0; j < 8; ++j) {
      a[j] += bf2f(v0[j]); b[j] += bf2f(v1[j]);
      c[j] += bf2f(v2[j]); d[j] += bf2f(v3[j]);
    }
  }
  for (; i < cnt; ++i) {
    int s0 = bucket[bs + i];
    s16x8 v0 = *(const s16x8*)(X + (size_t)s0 * 512 + lane * 8);
#pragma unroll
    for (int j = 0; j < 8; ++j) a[j] += bf2f(v0[j]);
  }
  float inv = 1.0f / (float)(cnt > 0 ? cnt : 1);
  s16x8 o;
#pragma unroll
  for (int j = 0; j < 8; ++j) o[j] = f2bf(((a[j] + b[j]) + (c[j] + d[j])) * inv);
  *(s16x8*)(out + (size_t)gw * 512 + lane * 8) = o;
}

// ---------------- bf16 MFMA GEMM: C[M,N] = [Aleft|Aright] (M x K, bf16) * Bt^T + bias ----------------
// Bt is N x K row-major (i.e. W^T), bf16. A is split at K/2 across two buffers, each ld = KH.
// BM x BN tile, BK=64, 4 waves (2x2): wave computes (BM/2)x(BN/2) via (BM/32)x(BN/32) frags
// of 16x16x32. LDS tiles XOR-swizzled (T2); staged with linear-dest global_load_lds +
// pre-swizzled global source (rule #21). r8-verified shapes: gemm0 128x128, gemm1 64x128.
template <int BM, int BN, bool RELU_BF16>
__global__ __launch_bounds__(256, 2) void gemm_k(
    const short* __restrict__ Aleft, const short* __restrict__ Aright,
    const short* __restrict__ Bt, const float* __restrict__ bias,
    void* __restrict__ Cout, int M, int N, int K, int KH) {
  constexpr int MFR = BM / 32;       // 16-row frags per wave in M
  constexpr int NFR = BN / 32;       // 16-col frags per wave in N
  constexpr int PA = BM / 32;        // 1KB staging chunks per wave for A
  constexpr int PB = BN / 32;        // 1KB staging chunks per wave for B
  __shared__ short As[BM * 64];
  __shared__ short Bs[BN * 64];
  const int tid = threadIdx.x;
  const int w = tid >> 6, lane = tid & 63;
  const int m0 = blockIdx.y * BM, n0 = blockIdx.x * BN;
  const int wr = w >> 1, wc = w & 1;
  const int lr = lane & 15, lk = (lane >> 4) << 3;

  f32x4 acc[MFR][NFR] = {};

  const int nkt = K >> 6;
  const int ktH = KH >> 6;
  const size_t ldA = (size_t)KH * 2;  // bytes
  const size_t ldB = (size_t)K * 2;   // bytes

  for (int kt = 0; kt < nkt; ++kt) {
    const char* Abase = (const char*)((kt < ktH) ? Aleft : Aright);
    const int ktl = (kt < ktH) ? kt : kt - ktH;
#pragma unroll
    for (int j = 0; j < PA; ++j) {
      int c = w * PA + j;
      int o = (c << 10) + lane * 16;             // byte offset in A tile
      int row = o >> 7;                          // 128 B per row (BK=64 bf16)
      int kb = o & 127;
      int kbs = kb ^ ((row & 7) << 4);           // pre-swizzled source column
      int ar = m0 + row; if (ar > M - 1) ar = M - 1;
      gld_lds16(Abase + (size_t)ar * ldA + (size_t)(ktl * 128 + kbs),
                ((char*)As) + (c << 10));
    }
#pragma unroll
    for (int j = 0; j < PB; ++j) {
      int c = w * PB + j;
      int o = (c << 10) + lane * 16;
      int row = o >> 7;                          // row in [0, BN)
      int kb = o & 127;
      int kbs = kb ^ ((row & 7) << 4);
      gld_lds16((const char*)Bt + (size_t)(n0 + row) * ldB + (size_t)(kt * 128 + kbs),
                ((char*)Bs) + (c << 10));
    }
    __syncthreads();
#pragma unroll
    for (int kk = 0; kk < 2; ++kk) {
      s16x8 af[MFR], bfr[NFR];
      const int kbyte = (kk * 32 + lk) * 2;
#pragma unroll
      for (int m = 0; m < MFR; ++m) {
        int r = wr * (BM / 2) + m * 16 + lr;
        af[m] = *(const s16x8*)((const char*)As + (r << 7) + (kbyte ^ ((r & 7) << 4)));
      }
#pragma unroll
      for (int n = 0; n < NFR; ++n) {
        int r = wc * (BN / 2) + n * 16 + lr;
        bfr[n] = *(const s16x8*)((const char*)Bs + (r << 7) + (kbyte ^ ((r & 7) << 4)));
      }
#pragma unroll
      for (int m = 0; m < MFR; ++m)
#pragma unroll
        for (int n = 0; n < NFR; ++n)
          acc[m][n] = __builtin_amdgcn_mfma_f32_16x16x32_bf16(af[m], bfr[n], acc[m][n], 0, 0, 0);
    }
    __syncthreads();
  }

  const int rq = (lane >> 4) * 4;
#pragma unroll
  for (int m = 0; m < MFR; ++m) {
#pragma unroll
    for (int n = 0; n < NFR; ++n) {
      const int col = n0 + wc * (BN / 2) + n * 16 + lr;
      const float bv = bias[col];
#pragma unroll
      for (int j = 0; j < 4; ++j) {
        const int row = m0 + wr * (BM / 2) + m * 16 + rq + j;
        if (row < M) {
          float v = acc[m][n][j] + bv;
          if (RELU_BF16) {
            v = v > 0.0f ? v : 0.0f;
            ((short*)Cout)[(size_t)row * N + col] = f2bf(v);
          } else {
            ((float*)Cout)[(size_t)row * N + col] = v;
          }
        }
      }
    }
  }
}

// ---------------- launcher ----------------
extern "C" void kernel_launch(void* const* d_in, const int* in_sizes, int n_in,
                              void* d_out, int out_size, void* d_ws, size_t ws_size,
                              hipStream_t stream) {
  const int NS0 = 200000, ND0 = 40000, ND1 = 8000;
  const int E0 = 1000000, E1 = 80000;
  const int DIN = 256, DH = 512, DOUT = 256;

  const float* feat = (const float*)d_in[0];
  const float* Wself0 = (const float*)d_in[1];
  const float* Wneigh0 = (const float*)d_in[2];
  const float* b0 = (const float*)d_in[3];
  const float* Wself1 = (const float*)d_in[4];
  const float* Wneigh1 = (const float*)d_in[5];
  const float* b1 = (const float*)d_in[6];
  const int* es0 = (const int*)d_in[7];
  const int* ed0 = (const int*)d_in[8];
  const int* es1 = (const int*)d_in[9];
  const int* ed1 = (const int*)d_in[10];

  char* w = (char*)d_ws;
  size_t pos = 0;
  auto take = [&](size_t b) -> char* {
    char* p = w + pos;
    pos += (b + 255) & ~(size_t)255;
    return p;
  };

  short* hne0 = (short*)take((size_t)ND0 * DIN * 2);
  short* h = (short*)take((size_t)ND0 * DH * 2);
  short* hne1 = (short*)take((size_t)ND1 * DH * 2);
  short* hdst0buf = (short*)take((size_t)ND0 * DIN * 2);
  short* W0T = (short*)take((size_t)DH * 2 * DIN * 2);
  short* W1T = (short*)take((size_t)DOUT * 2 * DH * 2);
  int* bucket0 = (int*)take((size_t)ND0 * 64 * 4);   // rows: [cnt | 63 slots]; 10,240,000 B
  int* bucket1 = (int*)take((size_t)ND1 * 48 * 4);   // rows: [cnt | 47 slots]; adjacent
  short* featbf = (short*)take((size_t)NS0 * DIN * 2);
  const bool use_bf = (ws_size >= pos);
  (void)in_sizes; (void)n_in; (void)out_size;

  // zero both bucket regions (counters live in slot 0 of each row)
  hipMemsetAsync(bucket0, 0, (size_t)(ND0 * 64 + ND1 * 48) * 4, stream);

  const short* hdst0 = use_bf ? featbf : hdst0buf;

  // fused front-end (r10 ordering): conv || W^T || fill0 || fill1
  front_k<<<2048, 256, 0, stream>>>(
      feat, use_bf ? featbf : hdst0buf,
      use_bf ? (long)NS0 * DIN : (long)ND0 * DIN,
      Wself0, Wneigh0, W0T, Wself1, Wneigh1, W1T,
      es0, ed0, E0, bucket0,
      es1, ed1, E1, bucket1);

  if (use_bf)
    agg_bf16_256<<<ND0 / 4, 256, 0, stream>>>(featbf, bucket0, hne0, ND0);
  else
    agg_f32_256<<<ND0 / 4, 256, 0, stream>>>(feat, bucket0, hne0, ND0);

  // layer 0 GEMM: (40000 x 512) = [feat[:40000] | hne0] @ [Wself0;Wneigh0], +b0, relu, bf16 out
  gemm_k<128, 128, true><<<dim3(DH / 128, (ND0 + 127) / 128), 256, 0, stream>>>(
      hdst0, hne0, W0T, b0, h, ND0, DH, 2 * DIN, DIN);

  agg_bf16_512<<<ND1 / 4, 256, 0, stream>>>(h, bucket1, hne1, ND1);

  // layer 1 GEMM: (8000 x 256) = [h[:8000] | hne1] @ [Wself1;Wneigh1], +b1, f32 out
  gemm_k<64, 128, false><<<dim3(DOUT / 128, (ND1 + 63) / 64), 256, 0, stream>>>(
      h, hne1, W1T, b1, d_out, ND1, DOUT, 2 * DH, DH);
}

// Round 13
// 249.296 us; speedup vs baseline: 1.1192x; 1.1192x over previous
//
#include <hip/hip_runtime.h>

#define DEV __device__ __forceinline__

typedef float f32x4 __attribute__((ext_vector_type(4)));
typedef short s16x4 __attribute__((ext_vector_type(4)));
typedef short s16x8 __attribute__((ext_vector_type(8)));

DEV float bf2f(short s) {
  unsigned u = ((unsigned)(unsigned short)s) << 16;
  return __builtin_bit_cast(float, u);
}
DEV short f2bf(float f) {
  unsigned u = __builtin_bit_cast(unsigned, f);
  u += 0x7FFFu + ((u >> 16) & 1u);   // RNE
  return (short)(u >> 16);
}

DEV void gld_lds16(const void* g, void* l) {
  __builtin_amdgcn_global_load_lds(
      (const __attribute__((address_space(1))) void*)g,
      (__attribute__((address_space(3))) void*)l, 16, 0, 0);
}

// ---------------- fused front-end, EXACTLY 2048 blocks = 1 dispatch round ----------------
// r10-verified best (251.4 us). Separate cnt arrays: atomics stay concentrated in 192 KB
// (r12's interleaved [cnt|slots] rows spread atomics over 10 MB and regressed +28 us).
// blocks [0,1664): f32->bf16 conv (BW-bound streaming)
// [1664,1728): both W^T builds | [1728,2016): fill0 | [2016,2048): fill1
// cnt0/cnt1 zeroed by the preceding memset (fill is in THIS dispatch -> can't self-zero).
__global__ void front_k(const float* __restrict__ feat, short* __restrict__ fbf, long nconv,
                        const float* __restrict__ Ws0, const float* __restrict__ Wn0,
                        short* __restrict__ W0T,
                        const float* __restrict__ Ws1, const float* __restrict__ Wn1,
                        short* __restrict__ W1T,
                        const int* __restrict__ es0, const int* __restrict__ ed0, int E0,
                        int* __restrict__ cnt0, int* __restrict__ bk0,
                        const int* __restrict__ es1, const int* __restrict__ ed1, int E1,
                        int* __restrict__ cnt1, int* __restrict__ bk1) {
  const int b = blockIdx.x, tid = threadIdx.x;
  if (b < 1664) {
    long i = ((long)b * 256 + tid) * 8;
    const long stride = (long)1664 * 256 * 8;
    for (; i < nconv; i += stride) {
      f32x4 v0 = *(const f32x4*)(feat + i);
      f32x4 v1 = *(const f32x4*)(feat + i + 4);
      s16x8 o;
      o[0] = f2bf(v0[0]); o[1] = f2bf(v0[1]); o[2] = f2bf(v0[2]); o[3] = f2bf(v0[3]);
      o[4] = f2bf(v1[0]); o[5] = f2bf(v1[1]); o[6] = f2bf(v1[2]); o[7] = f2bf(v1[3]);
      *(s16x8*)(fbf + i) = o;
    }
  } else if (b < 1728) {
    // combined W^T: idx in [0, 524288); first 262144 -> W0T (N=512,K=512), rest -> W1T (N=256,K=1024)
    for (int idx = (b - 1664) * 256 + tid; idx < 524288; idx += 64 * 256) {
      if (idx < 262144) {
        int n = idx >> 9, k = idx & 511;
        float v = (k < 256) ? Ws0[(size_t)k * 512 + n] : Wn0[(size_t)(k - 256) * 512 + n];
        W0T[idx] = f2bf(v);
      } else {
        int i2 = idx - 262144;
        int n = i2 >> 10, k = i2 & 1023;
        float v = (k < 512) ? Ws1[(size_t)k * 256 + n] : Wn1[(size_t)(k - 512) * 256 + n];
        W1T[i2] = f2bf(v);
      }
    }
  } else if (b < 2016) {
    for (int e = (b - 1728) * 256 + tid; e < E0; e += 288 * 256) {
      int d = ed0[e];
      int p = atomicAdd(&cnt0[d], 1);
      if (p < 64) bk0[(d << 6) + p] = es0[e];
    }
  } else {
    for (int e = (b - 2016) * 256 + tid; e < E1; e += 32 * 256) {
      int d = ed1[e];
      int p = atomicAdd(&cnt1[d], 1);
      if (p < 48) bk1[d * 48 + p] = es1[e];
    }
  }
}

// ---------------- mean aggregation: one wave per dst row (padded buckets) ----------------
__global__ void agg_f32_256(const float* __restrict__ X, const int* __restrict__ cntA,
                            const int* __restrict__ bucket, short* __restrict__ out,
                            int n_dst) {
  int gw = (blockIdx.x * blockDim.x + threadIdx.x) >> 6;
  if (gw >= n_dst) return;
  int lane = threadIdx.x & 63;
  int start = gw << 6, cnt = cntA[gw];
  float a[4] = {0, 0, 0, 0}, b[4] = {0, 0, 0, 0};
  int i = 0;
  for (; i + 2 <= cnt; i += 2) {
    int s0 = bucket[start + i], s1 = bucket[start + i + 1];
    f32x4 v0 = *(const f32x4*)(X + (size_t)s0 * 256 + lane * 4);
    f32x4 v1 = *(const f32x4*)(X + (size_t)s1 * 256 + lane * 4);
#pragma unroll
    for (int j = 0; j < 4; ++j) { a[j] += v0[j]; b[j] += v1[j]; }
  }
  if (i < cnt) {
    int s0 = bucket[start + i];
    f32x4 v0 = *(const f32x4*)(X + (size_t)s0 * 256 + lane * 4);
#pragma unroll
    for (int j = 0; j < 4; ++j) a[j] += v0[j];
  }
  float inv = 1.0f / (float)(cnt > 0 ? cnt : 1);
  s16x4 o;
#pragma unroll
  for (int j = 0; j < 4; ++j) o[j] = f2bf((a[j] + b[j]) * inv);
  *(s16x4*)(out + (size_t)gw * 256 + lane * 4) = o;
}

// 2-rows-per-instruction: lanes 0..31 even-slot, 32..63 odd-slot, 16 B/lane; cross-half
// shfl reduce at the end. (r8-verified version: 2 loads / 4 rows in flight.)
__global__ void agg_bf16_256(const short* __restrict__ X, const int* __restrict__ cntA,
                             const int* __restrict__ bucket, short* __restrict__ out,
                             int n_dst) {
  int gw = (blockIdx.x * blockDim.x + threadIdx.x) >> 6;
  if (gw >= n_dst) return;
  int lane = threadIdx.x & 63;
  int half = lane >> 5;        // which neighbor of the pair
  int cl = lane & 31;          // column group: cols cl*8 .. cl*8+7
  int start = gw << 6, cnt = cntA[gw];
  float a[8] = {0, 0, 0, 0, 0, 0, 0, 0}, b[8] = {0, 0, 0, 0, 0, 0, 0, 0};
  int i = 0;
  for (; i + 4 <= cnt; i += 4) {
    int s0 = bucket[start + i + half];
    int s1 = bucket[start + i + 2 + half];
    s16x8 v0 = *(const s16x8*)(X + (size_t)s0 * 256 + cl * 8);
    s16x8 v1 = *(const s16x8*)(X + (size_t)s1 * 256 + cl * 8);
#pragma unroll
    for (int j = 0; j < 8; ++j) { a[j] += bf2f(v0[j]); b[j] += bf2f(v1[j]); }
  }
  for (; i < cnt; i += 2) {            // tail: 1..3 neighbors, half-predicated
    int idx = i + half;
    if (idx < cnt) {
      int s0 = bucket[start + idx];
      s16x8 v0 = *(const s16x8*)(X + (size_t)s0 * 256 + cl * 8);
#pragma unroll
      for (int j = 0; j < 8; ++j) a[j] += bf2f(v0[j]);
    }
  }
  float inv = 1.0f / (float)(cnt > 0 ? cnt : 1);
  float r[8];
#pragma unroll
  for (int j = 0; j < 8; ++j) {
    float s = a[j] + b[j];
    r[j] = s + __shfl(s, lane ^ 32);   // combine the two neighbor subsets
  }
  if (half == 0) {
    s16x8 o;
#pragma unroll
    for (int j = 0; j < 8; ++j) o[j] = f2bf(r[j] * inv);
    *(s16x8*)(out + (size_t)gw * 256 + cl * 8) = o;
  }
}

// D=512: 16 B/lane across all 64 lanes; MLP via unroll-4. Padded bucket, PAD1=48.
__global__ void agg_bf16_512(const short* __restrict__ X, const int* __restrict__ cntA,
                             const int* __restrict__ bucket, short* __restrict__ out,
                             int n_dst) {
  int gw = (blockIdx.x * blockDim.x + threadIdx.x) >> 6;
  if (gw >= n_dst) return;
  int lane = threadIdx.x & 63;
  int start = gw * 48, cnt = cntA[gw];
  float a[8] = {0, 0, 0, 0, 0, 0, 0, 0}, b[8] = {0, 0, 0, 0, 0, 0, 0, 0};
  float c[8] = {0, 0, 0, 0, 0, 0, 0, 0}, d[8] = {0, 0, 0, 0, 0, 0, 0, 0};
  int i = 0;
  for (; i + 4 <= cnt; i += 4) {
    int s0 = bucket[start + i], s1 = bucket[start + i + 1];
    int s2 = bucket[start + i + 2], s3 = bucket[start + i + 3];
    s16x8 v0 = *(const s16x8*)(X + (size_t)s0 * 512 + lane * 8);
    s16x8 v1 = *(const s16x8*)(X + (size_t)s1 * 512 + lane * 8);
    s16x8 v2 = *(const s16x8*)(X + (size_t)s2 * 512 + lane * 8);
    s16x8 v3 = *(const s16x8*)(X + (size_t)s3 * 512 + lane * 8);
#pragma unroll
    for (int j = 0; j < 8; ++j) {
      a[j] += bf2f(v0[j]); b[j] += bf2f(v1[j]);
      c[j] += bf2f(v2[j]); d[j] += bf2f(v3[j]);
    }
  }
  for (; i < cnt; ++i) {
    int s0 = bucket[start + i];
    s16x8 v0 = *(const s16x8*)(X + (size_t)s0 * 512 + lane * 8);
#pragma unroll
    for (int j = 0; j < 8; ++j) a[j] += bf2f(v0[j]);
  }
  float inv = 1.0f / (float)(cnt > 0 ? cnt : 1);
  s16x8 o;
#pragma unroll
  for (int j = 0; j < 8; ++j) o[j] = f2bf(((a[j] + b[j]) + (c[j] + d[j])) * inv);
  *(s16x8*)(out + (size_t)gw * 512 + lane * 8) = o;
}

// ---------------- bf16 MFMA GEMM: C[M,N] = [Aleft|Aright] (M x K, bf16) * Bt^T + bias ----------------
// Bt is N x K row-major (i.e. W^T), bf16. A is split at K/2 across two buffers, each ld = KH.
// BM x BN tile, BK=64, 4 waves (2x2): wave computes (BM/2)x(BN/2) via (BM/32)x(BN/32) frags
// of 16x16x32. LDS tiles XOR-swizzled (T2); staged with linear-dest global_load_lds +
// pre-swizzled global source (rule #21). r8-verified shapes: gemm0 128x128, gemm1 64x128.
template <int BM, int BN, bool RELU_BF16>
__global__ __launch_bounds__(256, 2) void gemm_k(
    const short* __restrict__ Aleft, const short* __restrict__ Aright,
    const short* __restrict__ Bt, const float* __restrict__ bias,
    void* __restrict__ Cout, int M, int N, int K, int KH) {
  constexpr int MFR = BM / 32;       // 16-row frags per wave in M
  constexpr int NFR = BN / 32;       // 16-col frags per wave in N
  constexpr int PA = BM / 32;        // 1KB staging chunks per wave for A
  constexpr int PB = BN / 32;        // 1KB staging chunks per wave for B
  __shared__ short As[BM * 64];
  __shared__ short Bs[BN * 64];
  const int tid = threadIdx.x;
  const int w = tid >> 6, lane = tid & 63;
  const int m0 = blockIdx.y * BM, n0 = blockIdx.x * BN;
  const int wr = w >> 1, wc = w & 1;
  const int lr = lane & 15, lk = (lane >> 4) << 3;

  f32x4 acc[MFR][NFR] = {};

  const int nkt = K >> 6;
  const int ktH = KH >> 6;
  const size_t ldA = (size_t)KH * 2;  // bytes
  const size_t ldB = (size_t)K * 2;   // bytes

  for (int kt = 0; kt < nkt; ++kt) {
    const char* Abase = (const char*)((kt < ktH) ? Aleft : Aright);
    const int ktl = (kt < ktH) ? kt : kt - ktH;
#pragma unroll
    for (int j = 0; j < PA; ++j) {
      int c = w * PA + j;
      int o = (c << 10) + lane * 16;             // byte offset in A tile
      int row = o >> 7;                          // 128 B per row (BK=64 bf16)
      int kb = o & 127;
      int kbs = kb ^ ((row & 7) << 4);           // pre-swizzled source column
      int ar = m0 + row; if (ar > M - 1) ar = M - 1;
      gld_lds16(Abase + (size_t)ar * ldA + (size_t)(ktl * 128 + kbs),
                ((char*)As) + (c << 10));
    }
#pragma unroll
    for (int j = 0; j < PB; ++j) {
      int c = w * PB + j;
      int o = (c << 10) + lane * 16;
      int row = o >> 7;                          // row in [0, BN)
      int kb = o & 127;
      int kbs = kb ^ ((row & 7) << 4);
      gld_lds16((const char*)Bt + (size_t)(n0 + row) * ldB + (size_t)(kt * 128 + kbs),
                ((char*)Bs) + (c << 10));
    }
    __syncthreads();
#pragma unroll
    for (int kk = 0; kk < 2; ++kk) {
      s16x8 af[MFR], bfr[NFR];
      const int kbyte = (kk * 32 + lk) * 2;
#pragma unroll
      for (int m = 0; m < MFR; ++m) {
        int r = wr * (BM / 2) + m * 16 + lr;
        af[m] = *(const s16x8*)((const char*)As + (r << 7) + (kbyte ^ ((r & 7) << 4)));
      }
#pragma unroll
      for (int n = 0; n < NFR; ++n) {
        int r = wc * (BN / 2) + n * 16 + lr;
        bfr[n] = *(const s16x8*)((const char*)Bs + (r << 7) + (kbyte ^ ((r & 7) << 4)));
      }
#pragma unroll
      for (int m = 0; m < MFR; ++m)
#pragma unroll
        for (int n = 0; n < NFR; ++n)
          acc[m][n] = __builtin_amdgcn_mfma_f32_16x16x32_bf16(af[m], bfr[n], acc[m][n], 0, 0, 0);
    }
    __syncthreads();
  }

  const int rq = (lane >> 4) * 4;
#pragma unroll
  for (int m = 0; m < MFR; ++m) {
#pragma unroll
    for (int n = 0; n < NFR; ++n) {
      const int col = n0 + wc * (BN / 2) + n * 16 + lr;
      const float bv = bias[col];
#pragma unroll
      for (int j = 0; j < 4; ++j) {
        const int row = m0 + wr * (BM / 2) + m * 16 + rq + j;
        if (row < M) {
          float v = acc[m][n][j] + bv;
          if (RELU_BF16) {
            v = v > 0.0f ? v : 0.0f;
            ((short*)Cout)[(size_t)row * N + col] = f2bf(v);
          } else {
            ((float*)Cout)[(size_t)row * N + col] = v;
          }
        }
      }
    }
  }
}

// ---------------- launcher ----------------
extern "C" void kernel_launch(void* const* d_in, const int* in_sizes, int n_in,
                              void* d_out, int out_size, void* d_ws, size_t ws_size,
                              hipStream_t stream) {
  const int NS0 = 200000, ND0 = 40000, ND1 = 8000;
  const int E0 = 1000000, E1 = 80000;
  const int DIN = 256, DH = 512, DOUT = 256;

  const float* feat = (const float*)d_in[0];
  const float* Wself0 = (const float*)d_in[1];
  const float* Wneigh0 = (const float*)d_in[2];
  const float* b0 = (const float*)d_in[3];
  const float* Wself1 = (const float*)d_in[4];
  const float* Wneigh1 = (const float*)d_in[5];
  const float* b1 = (const float*)d_in[6];
  const int* es0 = (const int*)d_in[7];
  const int* ed0 = (const int*)d_in[8];
  const int* es1 = (const int*)d_in[9];
  const int* ed1 = (const int*)d_in[10];

  char* w = (char*)d_ws;
  size_t pos = 0;
  auto take = [&](size_t b) -> char* {
    char* p = w + pos;
    pos += (b + 255) & ~(size_t)255;
    return p;
  };

  short* hne0 = (short*)take((size_t)ND0 * DIN * 2);
  short* h = (short*)take((size_t)ND0 * DH * 2);
  short* hne1 = (short*)take((size_t)ND1 * DH * 2);
  short* hdst0buf = (short*)take((size_t)ND0 * DIN * 2);
  short* W0T = (short*)take((size_t)DH * 2 * DIN * 2);
  short* W1T = (short*)take((size_t)DOUT * 2 * DH * 2);
  int* cnt0 = (int*)take((size_t)ND0 * 4);   // cnt0 (160000 B, 256-aligned) then cnt1:
  int* cnt1 = (int*)take((size_t)ND1 * 4);   // adjacent -> one memset covers both
  int* bucket0 = (int*)take((size_t)ND0 * 64 * 4);   // PAD0=64
  int* bucket1 = (int*)take((size_t)ND1 * 48 * 4);   // PAD1=48
  short* featbf = (short*)take((size_t)NS0 * DIN * 2);
  const bool use_bf = (ws_size >= pos);
  (void)in_sizes; (void)n_in; (void)out_size;

  // zero both degree counters BEFORE the fused front (fill lives in front_k)
  hipMemsetAsync(cnt0, 0, (size_t)(ND0 + ND1) * 4, stream);

  const short* hdst0 = use_bf ? featbf : hdst0buf;

  // fused front-end: conv || W^T builds || both fills, 2048 blocks = 1 round
  front_k<<<2048, 256, 0, stream>>>(
      feat, use_bf ? featbf : hdst0buf,
      use_bf ? (long)NS0 * DIN : (long)ND0 * DIN,
      Wself0, Wneigh0, W0T, Wself1, Wneigh1, W1T,
      es0, ed0, E0, cnt0, bucket0,
      es1, ed1, E1, cnt1, bucket1);

  if (use_bf)
    agg_bf16_256<<<ND0 / 4, 256, 0, stream>>>(featbf, cnt0, bucket0, hne0, ND0);
  else
    agg_f32_256<<<ND0 / 4, 256, 0, stream>>>(feat, cnt0, bucket0, hne0, ND0);

  // layer 0 GEMM: (40000 x 512) = [feat[:40000] | hne0] @ [Wself0;Wneigh0], +b0, relu, bf16 out
  gemm_k<128, 128, true><<<dim3(DH / 128, (ND0 + 127) / 128), 256, 0, stream>>>(
      hdst0, hne0, W0T, b0, h, ND0, DH, 2 * DIN, DIN);

  agg_bf16_512<<<ND1 / 4, 256, 0, stream>>>(h, cnt1, bucket1, hne1, ND1);

  // layer 1 GEMM: (8000 x 256) = [h[:8000] | hne1] @ [Wself1;Wneigh1], +b1, f32 out
  gemm_k<64, 128, false><<<dim3(DOUT / 128, (ND1 + 63) / 64), 256, 0, stream>>>(
      h, hne1, W1T, b1, d_out, ND1, DOUT, 2 * DH, DH);
}